// Round 3
// baseline (195.295 us; speedup 1.0000x reference)
//
#include <hip/hip_runtime.h>
#include <hip/hip_bf16.h>
#include <stdint.h>

typedef __attribute__((ext_vector_type(8))) short short8;
typedef __attribute__((ext_vector_type(4))) float float4v;

#define SEQ   1024
#define NQKV  3072

__device__ __forceinline__ float bf2f(ushort h) {
    union { uint u; float f; } c; c.u = ((uint)h) << 16; return c.f;
}
__device__ __forceinline__ ushort f2bf(float f) {
    union { uint u; float f; } c; c.f = f;
    uint u = c.u;
    return (ushort)((u + 0x7fffu + ((u >> 16) & 1u)) >> 16);
}
__device__ __forceinline__ uint cvt_pk_bf16(float lo, float hi) {
    uint r;
    asm volatile("v_cvt_pk_bf16_f32 %0, %1, %2" : "=v"(r) : "v"(lo), "v"(hi));
    return r;
}
__device__ __forceinline__ void gl2lds16(const ushort* g, ushort* l) {
    __builtin_amdgcn_global_load_lds(
        (const __attribute__((address_space(1))) unsigned int*)(g),
        (__attribute__((address_space(3))) unsigned int*)(l),
        16, 0, 0);
}

// ---------------------------------------------------------------------------
// prep_k: fused detect + X-convert + bias-concat + 4x weight transpose.
// Every block re-derives the dtype flag from X[0:256] via ballot popcount.
// Block layout: [0,4096) xcvt | [4096,4112) biascat | [4112,5136) transpose.
// ---------------------------------------------------------------------------
__global__ __launch_bounds__(256) void prep_k(const void* __restrict__ X,
                                              const void* __restrict__ w0,
                                              const void* __restrict__ w1,
                                              const void* __restrict__ w2,
                                              const void* __restrict__ w3,
                                              const void* __restrict__ bq,
                                              const void* __restrict__ bk,
                                              const void* __restrict__ bv,
                                              const void* __restrict__ bo,
                                              ushort* __restrict__ xc,
                                              ushort* __restrict__ biasout,
                                              ushort* __restrict__ wtall,
                                              int* __restrict__ flag) {
    __shared__ int tot;
    __shared__ ushort tile[64][72];
    int t = threadIdx.x;
    if (t == 0) tot = 0;
    __syncthreads();
    uint wv = ((const uint*)X)[t];
    uint e = (wv >> 7) & 0xFFu;
    bool isbf = (e >= 100u && e <= 130u);
    unsigned long long m = __ballot(isbf);
    if ((t & 63) == 0) atomicAdd(&tot, __popcll(m));
    __syncthreads();
    bool isf = (tot <= 128);   // true -> fp32 input

    int bi = blockIdx.x;
    if (bi == 0 && t == 0) flag[0] = isf ? 1 : 0;

    if (bi < 4096) {
        if (!isf) return;
        int i = (bi * 256 + t) * 4;
        float4 v = *(const float4*)((const float*)X + i);
        ushort4 o;
        o.x = f2bf(v.x); o.y = f2bf(v.y); o.z = f2bf(v.z); o.w = f2bf(v.w);
        *(ushort4*)(xc + i) = o;
    } else if (bi < 4112) {
        int i = (bi - 4096) * 256 + t;
        int sel = i >> 10, j = i & 1023;
        const void* p = (sel == 0) ? bq : (sel == 1) ? bk : (sel == 2) ? bv : bo;
        biasout[i] = isf ? f2bf(((const float*)p)[j]) : ((const ushort*)p)[j];
    } else {
        int idx = bi - 4112;
        int z = idx >> 8, rem = idx & 255;
        const void* in = (z == 0) ? w0 : (z == 1) ? w1 : (z == 2) ? w2 : w3;
        ushort* out = wtall + (size_t)z * 1024 * 1024;
        int k0 = (rem & 15) * 64, n0 = (rem >> 4) * 64;
        int r = t >> 3, c = (t & 7) * 8;
#pragma unroll
        for (int p = 0; p < 2; p++) {
            int rr = r + p * 32;
            if (isf) {
                const float* src = (const float*)in + (size_t)(k0 + rr) * 1024 + n0 + c;
                float4 v0 = *(const float4*)src;
                float4 v1 = *(const float4*)(src + 4);
                tile[rr][c + 0] = f2bf(v0.x); tile[rr][c + 1] = f2bf(v0.y);
                tile[rr][c + 2] = f2bf(v0.z); tile[rr][c + 3] = f2bf(v0.w);
                tile[rr][c + 4] = f2bf(v1.x); tile[rr][c + 5] = f2bf(v1.y);
                tile[rr][c + 6] = f2bf(v1.z); tile[rr][c + 7] = f2bf(v1.w);
            } else {
                uint4 v = *(const uint4*)((const ushort*)in + (size_t)(k0 + rr) * 1024 + n0 + c);
                *(uint4*)&tile[rr][c] = v;
            }
        }
        __syncthreads();
#pragma unroll
        for (int p = 0; p < 2; p++) {
            int n = r + p * 32;
            ushort vals[8];
#pragma unroll
            for (int j = 0; j < 8; j++) vals[j] = tile[c + j][n];
            *(uint4*)(out + (size_t)(n0 + n) * 1024 + k0 + c) = *(uint4*)vals;
        }
    }
}

// ---------------------------------------------------------------------------
// GEMM, BK=32 DOUBLE-BUFFERED, single barrier per K-iter (R5 attn pattern).
// BM x 128 tile, 4 waves (2x2). Chunk swizzle slot = kc ^ ((row>>1)&3)
// (conflict-free, R7-verified). A-pointer selected device-side per *flag.
// DUAL: fp32/bf16 store per flag.
// WRV: blocks with n0 >= 2048 (the V third of QKV) also emit the transposed
// copy VT[bh][d][t] directly from the accumulator: each lane's acc[r][cc]
// holds 4 CONSECUTIVE tokens (q*4+i) at fixed n -> one ushort4 store per
// (r,cc). Replaces the standalone vtrans kernel (bit-identical values:
// f2bf(acc+bias), same as vtrans read from QKV's bf16 store).
// ---------------------------------------------------------------------------
template <int BM, bool DUAL, bool WRV>
__global__ __launch_bounds__(256) void gemm_k(const ushort* __restrict__ Araw,
                                              const ushort* __restrict__ Aconv,
                                              const ushort* __restrict__ BT,
                                              const ushort* __restrict__ bias,
                                              void* __restrict__ C,
                                              ushort* __restrict__ vt,
                                              const int* __restrict__ flag,
                                              int M, int N, int K) {
    constexpr int RM = BM / 32;   // M-frags per wave
    constexpr int AJ = BM / 64;   // A-chunks per thread (BM*4/256)
    __shared__ ushort As[2][BM * 32];
    __shared__ ushort Bs[2][128 * 32];
    int n0 = blockIdx.x * 128, m0 = blockIdx.y * BM;
    int t = threadIdx.x;
    int w = t >> 6, lane = t & 63, q = lane >> 4, ln = lane & 15;
    int wr = w >> 1, wc = w & 1;
    const ushort* A = (*flag) ? Aconv : Araw;

    float4v acc[RM][4];
#pragma unroll
    for (int r = 0; r < RM; r++)
#pragma unroll
        for (int cc = 0; cc < 4; cc++) acc[r][cc] = (float4v){0.f, 0.f, 0.f, 0.f};

    // prologue: stage k0=0 into buf 0
#pragma unroll
    for (int j = 0; j < AJ; j++) {
        int c = j * 256 + t;
        int row = c >> 2, s = c & 3;
        int kc = s ^ ((row >> 1) & 3);
        gl2lds16(A + (size_t)(m0 + row) * K + kc * 8, &As[0][c * 8]);
    }
#pragma unroll
    for (int j = 0; j < 2; j++) {
        int c = j * 256 + t;
        int row = c >> 2, s = c & 3;
        int kc = s ^ ((row >> 1) & 3);
        gl2lds16(BT + (size_t)(n0 + row) * K + kc * 8, &Bs[0][c * 8]);
    }

    int nIter = K >> 5;
    for (int kt = 0; kt < nIter; kt++) {
        int cur = kt & 1;
        __syncthreads();   // buf[cur] staged; buf[cur^1] reads complete
        if (kt + 1 < nIter) {
            int nk0 = (kt + 1) << 5, nxt = cur ^ 1;
#pragma unroll
            for (int j = 0; j < AJ; j++) {
                int c = j * 256 + t;
                int row = c >> 2, s = c & 3;
                int kc = s ^ ((row >> 1) & 3);
                gl2lds16(A + (size_t)(m0 + row) * K + nk0 + kc * 8, &As[nxt][c * 8]);
            }
#pragma unroll
            for (int j = 0; j < 2; j++) {
                int c = j * 256 + t;
                int row = c >> 2, s = c & 3;
                int kc = s ^ ((row >> 1) & 3);
                gl2lds16(BT + (size_t)(n0 + row) * K + nk0 + kc * 8, &Bs[nxt][c * 8]);
            }
        }
        short8 af[RM], bf[4];
#pragma unroll
        for (int r = 0; r < RM; r++) {
            int row = wr * (BM / 2) + r * 16 + ln;
            af[r] = *(const short8*)&As[cur][((row << 2) | (q ^ ((row >> 1) & 3))) * 8];
        }
#pragma unroll
        for (int cc = 0; cc < 4; cc++) {
            int col = wc * 64 + cc * 16 + ln;
            bf[cc] = *(const short8*)&Bs[cur][((col << 2) | (q ^ ((col >> 1) & 3))) * 8];
        }
#pragma unroll
        for (int r = 0; r < RM; r++)
#pragma unroll
            for (int cc = 0; cc < 4; cc++)
                acc[r][cc] = __builtin_amdgcn_mfma_f32_16x16x32_bf16(af[r], bf[cc], acc[r][cc], 0, 0, 0);
    }

    bool outf = DUAL && (*flag != 0);
    bool wrv = WRV && (n0 >= 2048);
#pragma unroll
    for (int cc = 0; cc < 4; cc++) {
        int n = n0 + wc * 64 + cc * 16 + ln;
        float bs = bf2f(bias[n]);
#pragma unroll
        for (int r = 0; r < RM; r++) {
            ushort pk[4];
#pragma unroll
            for (int i = 0; i < 4; i++) {
                int m = m0 + wr * (BM / 2) + r * 16 + q * 4 + i;
                float v = acc[r][cc][i] + bs;
                if (outf) ((float*)C)[(size_t)m * N + n] = v;
                else      ((ushort*)C)[(size_t)m * N + n] = f2bf(v);
                pk[i] = f2bf(v);
            }
            if (wrv) {
                int mb = m0 + wr * (BM / 2) + r * 16 + q * 4;   // 4 consecutive tokens
                int b = mb >> 10, trow = mb & 1023;
                int h = (n - 2048) >> 6, d = n & 63;
                *(ushort4*)(vt + (((size_t)(b * 16 + h) * 64 + d) * 1024 + trow)) = *(ushort4*)pk;
            }
        }
    }
}

// ---------------------------------------------------------------------------
// Flash attention, causal, WAVE-SPLIT ADJACENT-PAIR dual-tile, pipelined,
// no-max softmax. Grid (8,64) x 512 threads: block r owns q-tiles 2r (waves
// 0-3) and 2r+1 (waves 4-7). Loop runs 2r+2 iterations (vs 16-pr for the
// old (pr,15-pr) pairing: total block-iters per bh 100 -> 72, and the two
// wave groups are compute-balanced: 2r+1 vs 2r+2 active iters). Same
// kt-ascending summation order -> bit-identical output.
// SWAPPED QK^T (T12): s = mfma(K, Q) so each lane holds S[t=nb*16+q*4+i]
// [srow=ln] -> P-write is 4x ds_write_b64 via v_cvt_pk_bf16_f32, l-partial
// is one scalar per lane. T5: s_setprio(1) around MFMA clusters.
// Faithful reshape: z[b,h,s,d] -> Z'[b][h*64 + s/16][(s%16)*64 + d]
// ---------------------------------------------------------------------------
__global__ __launch_bounds__(512) void attn_k(const ushort* __restrict__ qkv,
                                              const ushort* __restrict__ vt,
                                              ushort* __restrict__ zp) {
    __shared__ ushort Ks[2][64 * 64];
    __shared__ ushort Vs[2][64 * 64];
    __shared__ ushort P[8][16 * 76];
    int pr = blockIdx.x;
    int bh = blockIdx.y;
    int b = bh >> 4, h = bh & 15;
    int t = threadIdx.x;
    int w = t >> 6;
    int grp = w >> 2;
    int lane = t & 63, q = lane >> 4, ln = lane & 15;

    const float CE = 0.72134752f;    // 0.5 * log2(e)

    const ushort* Qp = qkv + (size_t)(b * SEQ) * NQKV + h * 64;
    const ushort* Kp = qkv + (size_t)(b * SEQ) * NQKV + 1024 + h * 64;
    const ushort* Vt = vt + (size_t)bh * 64 * 1024;

    int row0 = t >> 3, kc0 = (t & 7) ^ (row0 & 7);

    int tiB = 2 * pr + 1;            // group-B tile = loop bound
    int ti = grp ? tiB : (tiB - 1);  // group-A tile = 2r
    int sw = ti * 64 + (w & 3) * 16;

    short8 aq0 = *(const short8*)(Qp + (size_t)(sw + ln) * NQKV + q * 8);
    short8 aq1 = *(const short8*)(Qp + (size_t)(sw + ln) * NQKV + 32 + q * 8);

    float lp = 0.f;
    float4v o[4];
#pragma unroll
    for (int nb = 0; nb < 4; nb++) o[nb] = (float4v){0.f, 0.f, 0.f, 0.f};

    gl2lds16(Kp + (size_t)row0 * NQKV + kc0 * 8, &Ks[0][t * 8]);
    gl2lds16(Vt + (size_t)row0 * 1024 + kc0 * 8, &Vs[0][t * 8]);

    int srow_l = sw + ln;   // this lane's q-row (post-swap: srow = ln axis)

    for (int kt = 0; kt <= tiB; kt++) {
        int cur = kt & 1;
        int t0 = kt * 64;
        __syncthreads();
        if (kt < tiB) {
            int nt0 = t0 + 64, nxt = cur ^ 1;
            gl2lds16(Kp + (size_t)(nt0 + row0) * NQKV + kc0 * 8, &Ks[nxt][t * 8]);
            gl2lds16(Vt + (size_t)row0 * 1024 + nt0 + kc0 * 8, &Vs[nxt][t * 8]);
        }
        if (kt <= ti) {
            float4v s[4];
            __builtin_amdgcn_s_setprio(1);
#pragma unroll
            for (int nb = 0; nb < 4; nb++) {
                int row = nb * 16 + ln;
                short8 kf0 = *(const short8*)&Ks[cur][((row << 3) | (q ^ (row & 7))) * 8];
                short8 kf1 = *(const short8*)&Ks[cur][((row << 3) | ((4 + q) ^ (row & 7))) * 8];
                s[nb] = (float4v){0.f, 0.f, 0.f, 0.f};
                s[nb] = __builtin_amdgcn_mfma_f32_16x16x32_bf16(kf0, aq0, s[nb], 0, 0, 0);
                s[nb] = __builtin_amdgcn_mfma_f32_16x16x32_bf16(kf1, aq1, s[nb], 0, 0, 0);
            }
            __builtin_amdgcn_s_setprio(0);
            float p[4][4];
            if (kt < ti) {
#pragma unroll
                for (int nb = 0; nb < 4; nb++)
#pragma unroll
                    for (int i = 0; i < 4; i++) p[nb][i] = exp2f(s[nb][i] * CE);
            } else {
#pragma unroll
                for (int nb = 0; nb < 4; nb++)
#pragma unroll
                    for (int i = 0; i < 4; i++) {
                        int tcol = t0 + nb * 16 + q * 4 + i;
                        p[nb][i] = exp2f((tcol <= srow_l) ? s[nb][i] * CE : -1e30f);
                    }
            }
#pragma unroll
            for (int nb = 0; nb < 4; nb++)
                lp += (p[nb][0] + p[nb][1]) + (p[nb][2] + p[nb][3]);
#pragma unroll
            for (int nb = 0; nb < 4; nb++) {
                uint2 pk;
                pk.x = cvt_pk_bf16(p[nb][0], p[nb][1]);
                pk.y = cvt_pk_bf16(p[nb][2], p[nb][3]);
                *(uint2*)&P[w][ln * 76 + nb * 16 + q * 4] = pk;
            }
            asm volatile("s_waitcnt lgkmcnt(0)\n" ::: "memory");
            short8 ap0 = *(const short8*)&P[w][ln * 76 + q * 8];
            short8 ap1 = *(const short8*)&P[w][ln * 76 + 32 + q * 8];
            __builtin_amdgcn_s_setprio(1);
#pragma unroll
            for (int nb = 0; nb < 4; nb++) {
                int row = nb * 16 + ln;
                short8 bv0 = *(const short8*)&Vs[cur][((row << 3) | (q ^ (row & 7))) * 8];
                short8 bv1 = *(const short8*)&Vs[cur][((row << 3) | ((4 + q) ^ (row & 7))) * 8];
                o[nb] = __builtin_amdgcn_mfma_f32_16x16x32_bf16(ap0, bv0, o[nb], 0, 0, 0);
                o[nb] = __builtin_amdgcn_mfma_f32_16x16x32_bf16(ap1, bv1, o[nb], 0, 0, 0);
            }
            __builtin_amdgcn_s_setprio(0);
        }
    }

    // l[srow=ln] lives per-lane; reduce partial sums across the q axis.
    float lred = lp;
    lred += __shfl_xor(lred, 16, 64);
    lred += __shfl_xor(lred, 32, 64);
    // broadcast l for the o-fragment rows (srow = sw + q*4 + i)
    float l_i[4];
#pragma unroll
    for (int i = 0; i < 4; i++)
        l_i[i] = __shfl(lred, (q << 4) | (q * 4 + i), 64);

#pragma unroll
    for (int nb = 0; nb < 4; nb++) {
#pragma unroll
        for (int i = 0; i < 4; i++) {
            int srow = sw + q * 4 + i;
            int d = nb * 16 + ln;
            float z = o[nb][i] / l_i[i];
            int sp = h * 64 + (srow >> 4);
            int ep = ((srow & 15) << 6) + d;
            zp[((size_t)(b * SEQ + sp)) * 1024 + ep] = f2bf(z);
        }
    }
}

// ---------------------------------------------------------------------------
extern "C" void kernel_launch(void* const* d_in, const int* in_sizes, int n_in,
                              void* d_out, int out_size, void* d_ws, size_t ws_size,
                              hipStream_t stream) {
    const void* X  = d_in[0];
    // d_in[1] = mask (causal; applied structurally)
    const void* wq = d_in[2];
    const void* bq = d_in[3];
    const void* wk = d_in[4];
    const void* bk = d_in[5];
    const void* wv = d_in[6];
    const void* bv = d_in[7];
    const void* wo = d_in[8];
    const void* bo = d_in[9];

    char* ws = (char*)d_ws;
    int*    flag  = (int*)ws;                          // [0, 4096)
    ushort* biasq = (ushort*)(ws + 4096);              // 4096 bf16: [bq|bk|bv|bo]
    ushort* WTall = (ushort*)(ws + 12288);             // 4x 1024x1024 bf16 [wq|wk|wv|wo]
    ushort* Xc    = (ushort*)(ws + 8400896);           // 4096x1024 bf16 (fp32 path)
    ushort* QKV   = (ushort*)(ws + 16789504);          // 4096x3072 bf16
    ushort* VT    = (ushort*)(ws + 41955328);          // 64 x 64 x 1024 bf16
    ushort* WTo   = WTall + 3 * 1024 * 1024;
    ushort* ZP    = Xc;                                // alias: Xc dead after QKV gemm

    prep_k<<<5136, 256, 0, stream>>>(X, wq, wk, wv, wo, bq, bk, bv, bo,
                                     Xc, biasq, WTall, flag);
    gemm_k<128, false, true><<<dim3(24, 32), 256, 0, stream>>>(
        (const ushort*)X, Xc, WTall, biasq, QKV, VT, flag, 4096, NQKV, 1024);
    attn_k<<<dim3(8, 64), 512, 0, stream>>>(QKV, VT, ZP);
    gemm_k<64, true, false><<<dim3(8, 64), 256, 0, stream>>>(
        ZP, ZP, WTo, biasq + 3072, d_out, nullptr, flag, 4096, 1024, 1024);
}

// Round 4
// 184.076 us; speedup vs baseline: 1.0609x; 1.0609x over previous
//
#include <hip/hip_runtime.h>
#include <hip/hip_bf16.h>
#include <stdint.h>

typedef __attribute__((ext_vector_type(8))) short short8;
typedef __attribute__((ext_vector_type(4))) float float4v;

#define SEQ   1024
#define NQKV  3072

__device__ __forceinline__ float bf2f(ushort h) {
    union { uint u; float f; } c; c.u = ((uint)h) << 16; return c.f;
}
__device__ __forceinline__ ushort f2bf(float f) {
    union { uint u; float f; } c; c.f = f;
    uint u = c.u;
    return (ushort)((u + 0x7fffu + ((u >> 16) & 1u)) >> 16);
}
__device__ __forceinline__ uint cvt_pk_bf16(float lo, float hi) {
    uint r;
    asm volatile("v_cvt_pk_bf16_f32 %0, %1, %2" : "=v"(r) : "v"(lo), "v"(hi));
    return r;
}
__device__ __forceinline__ void gl2lds16(const ushort* g, ushort* l) {
    __builtin_amdgcn_global_load_lds(
        (const __attribute__((address_space(1))) unsigned int*)(g),
        (__attribute__((address_space(3))) unsigned int*)(l),
        16, 0, 0);
}

// ---------------------------------------------------------------------------
// prep_k: fused detect + X-convert + bias-concat + 4x weight transpose.
// ---------------------------------------------------------------------------
__global__ __launch_bounds__(256) void prep_k(const void* __restrict__ X,
                                              const void* __restrict__ w0,
                                              const void* __restrict__ w1,
                                              const void* __restrict__ w2,
                                              const void* __restrict__ w3,
                                              const void* __restrict__ bq,
                                              const void* __restrict__ bk,
                                              const void* __restrict__ bv,
                                              const void* __restrict__ bo,
                                              ushort* __restrict__ xc,
                                              ushort* __restrict__ biasout,
                                              ushort* __restrict__ wtall,
                                              int* __restrict__ flag) {
    __shared__ int tot;
    __shared__ ushort tile[64][72];
    int t = threadIdx.x;
    if (t == 0) tot = 0;
    __syncthreads();
    uint wv = ((const uint*)X)[t];
    uint e = (wv >> 7) & 0xFFu;
    bool isbf = (e >= 100u && e <= 130u);
    unsigned long long m = __ballot(isbf);
    if ((t & 63) == 0) atomicAdd(&tot, __popcll(m));
    __syncthreads();
    bool isf = (tot <= 128);   // true -> fp32 input

    int bi = blockIdx.x;
    if (bi == 0 && t == 0) flag[0] = isf ? 1 : 0;

    if (bi < 4096) {
        if (!isf) return;
        int i = (bi * 256 + t) * 4;
        float4 v = *(const float4*)((const float*)X + i);
        ushort4 o;
        o.x = f2bf(v.x); o.y = f2bf(v.y); o.z = f2bf(v.z); o.w = f2bf(v.w);
        *(ushort4*)(xc + i) = o;
    } else if (bi < 4112) {
        int i = (bi - 4096) * 256 + t;
        int sel = i >> 10, j = i & 1023;
        const void* p = (sel == 0) ? bq : (sel == 1) ? bk : (sel == 2) ? bv : bo;
        biasout[i] = isf ? f2bf(((const float*)p)[j]) : ((const ushort*)p)[j];
    } else {
        int idx = bi - 4112;
        int z = idx >> 8, rem = idx & 255;
        const void* in = (z == 0) ? w0 : (z == 1) ? w1 : (z == 2) ? w2 : w3;
        ushort* out = wtall + (size_t)z * 1024 * 1024;
        int k0 = (rem & 15) * 64, n0 = (rem >> 4) * 64;
        int r = t >> 3, c = (t & 7) * 8;
#pragma unroll
        for (int p = 0; p < 2; p++) {
            int rr = r + p * 32;
            if (isf) {
                const float* src = (const float*)in + (size_t)(k0 + rr) * 1024 + n0 + c;
                float4 v0 = *(const float4*)src;
                float4 v1 = *(const float4*)(src + 4);
                tile[rr][c + 0] = f2bf(v0.x); tile[rr][c + 1] = f2bf(v0.y);
                tile[rr][c + 2] = f2bf(v0.z); tile[rr][c + 3] = f2bf(v0.w);
                tile[rr][c + 4] = f2bf(v1.x); tile[rr][c + 5] = f2bf(v1.y);
                tile[rr][c + 6] = f2bf(v1.z); tile[rr][c + 7] = f2bf(v1.w);
            } else {
                uint4 v = *(const uint4*)((const ushort*)in + (size_t)(k0 + rr) * 1024 + n0 + c);
                *(uint4*)&tile[rr][c] = v;
            }
        }
        __syncthreads();
#pragma unroll
        for (int p = 0; p < 2; p++) {
            int n = r + p * 32;
            ushort vals[8];
#pragma unroll
            for (int j = 0; j < 8; j++) vals[j] = tile[c + j][n];
            *(uint4*)(out + (size_t)(n0 + n) * 1024 + k0 + c) = *(uint4*)vals;
        }
    }
}

// ---------------------------------------------------------------------------
// GEMM, BK=64 DOUBLE-BUFFERED, single barrier per K-iter. 16 K-iters at
// K=1024 (was 32 at BK=32): halves barrier+vmcnt-drain crossings, 32 MFMA
// per wave per iter. Chunk swizzle: 8 chunks/row, slot = s ^ (row & 7);
// row stride = 128B = all 32 banks, so 8 consecutive rows cover all 8
// 16B slots -> 2-way max bank aliasing (free). Same K accumulation order
// as BK=32 -> bit-identical output.
// WRV: QKV V-third blocks also emit VT[bh][d][t] from the accumulator
// (4 consecutive tokens per lane -> ushort4 store), replacing vtrans_k.
// ---------------------------------------------------------------------------
template <int BM, bool DUAL, bool WRV>
__global__ __launch_bounds__(256) void gemm_k(const ushort* __restrict__ Araw,
                                              const ushort* __restrict__ Aconv,
                                              const ushort* __restrict__ BT,
                                              const ushort* __restrict__ bias,
                                              void* __restrict__ C,
                                              ushort* __restrict__ vt,
                                              const int* __restrict__ flag,
                                              int M, int N, int K) {
    constexpr int RM = BM / 32;   // M-frags per wave
    constexpr int AJ = BM / 32;   // A-chunk rounds: BM rows * 8 chunks / 256 thr
    __shared__ ushort As[2][BM * 64];
    __shared__ ushort Bs[2][128 * 64];
    int n0 = blockIdx.x * 128, m0 = blockIdx.y * BM;
    int t = threadIdx.x;
    int w = t >> 6, lane = t & 63, q = lane >> 4, ln = lane & 15;
    int wr = w >> 1, wc = w & 1;
    const ushort* A = (*flag) ? Aconv : Araw;

    float4v acc[RM][4];
#pragma unroll
    for (int r = 0; r < RM; r++)
#pragma unroll
        for (int cc = 0; cc < 4; cc++) acc[r][cc] = (float4v){0.f, 0.f, 0.f, 0.f};

    // prologue: stage k0=0 into buf 0
#pragma unroll
    for (int j = 0; j < AJ; j++) {
        int c = j * 256 + t;
        int row = c >> 3, s = c & 7;
        int kc = s ^ (row & 7);
        gl2lds16(A + (size_t)(m0 + row) * K + kc * 8, &As[0][c * 8]);
    }
#pragma unroll
    for (int j = 0; j < 4; j++) {
        int c = j * 256 + t;
        int row = c >> 3, s = c & 7;
        int kc = s ^ (row & 7);
        gl2lds16(BT + (size_t)(n0 + row) * K + kc * 8, &Bs[0][c * 8]);
    }

    int nIter = K >> 6;
    for (int kt = 0; kt < nIter; kt++) {
        int cur = kt & 1;
        __syncthreads();   // buf[cur] staged; buf[cur^1] reads complete
        if (kt + 1 < nIter) {
            int nk0 = (kt + 1) << 6, nxt = cur ^ 1;
#pragma unroll
            for (int j = 0; j < AJ; j++) {
                int c = j * 256 + t;
                int row = c >> 3, s = c & 7;
                int kc = s ^ (row & 7);
                gl2lds16(A + (size_t)(m0 + row) * K + nk0 + kc * 8, &As[nxt][c * 8]);
            }
#pragma unroll
            for (int j = 0; j < 4; j++) {
                int c = j * 256 + t;
                int row = c >> 3, s = c & 7;
                int kc = s ^ (row & 7);
                gl2lds16(BT + (size_t)(n0 + row) * K + nk0 + kc * 8, &Bs[nxt][c * 8]);
            }
        }
#pragma unroll
        for (int kh = 0; kh < 2; kh++) {
            short8 af[RM], bf[4];
#pragma unroll
            for (int r = 0; r < RM; r++) {
                int row = wr * (BM / 2) + r * 16 + ln;
                af[r] = *(const short8*)&As[cur][((row << 3) | ((kh * 4 + q) ^ (row & 7))) * 8];
            }
#pragma unroll
            for (int cc = 0; cc < 4; cc++) {
                int col = wc * 64 + cc * 16 + ln;
                bf[cc] = *(const short8*)&Bs[cur][((col << 3) | ((kh * 4 + q) ^ (col & 7))) * 8];
            }
#pragma unroll
            for (int r = 0; r < RM; r++)
#pragma unroll
                for (int cc = 0; cc < 4; cc++)
                    acc[r][cc] = __builtin_amdgcn_mfma_f32_16x16x32_bf16(af[r], bf[cc], acc[r][cc], 0, 0, 0);
        }
    }

    bool outf = DUAL && (*flag != 0);
    bool wrv = WRV && (n0 >= 2048);
#pragma unroll
    for (int cc = 0; cc < 4; cc++) {
        int n = n0 + wc * 64 + cc * 16 + ln;
        float bs = bf2f(bias[n]);
#pragma unroll
        for (int r = 0; r < RM; r++) {
            ushort pk[4];
#pragma unroll
            for (int i = 0; i < 4; i++) {
                int m = m0 + wr * (BM / 2) + r * 16 + q * 4 + i;
                float v = acc[r][cc][i] + bs;
                if (outf) ((float*)C)[(size_t)m * N + n] = v;
                else      ((ushort*)C)[(size_t)m * N + n] = f2bf(v);
                pk[i] = f2bf(v);
            }
            if (wrv) {
                int mb = m0 + wr * (BM / 2) + r * 16 + q * 4;   // 4 consecutive tokens
                int b = mb >> 10, trow = mb & 1023;
                int h = (n - 2048) >> 6, d = n & 63;
                *(ushort4*)(vt + (((size_t)(b * 16 + h) * 64 + d) * 1024 + trow)) = *(ushort4*)pk;
            }
        }
    }
}

// ---------------------------------------------------------------------------
// Flash attention, causal, WAVE-SPLIT shared-prefix dual-tile (pr, 15-pr),
// pipelined, no-max softmax. Balanced: every block does exactly 17 active
// wave-group iterations (group A: pr+1, group B: 16-pr) -- do NOT "optimize"
// the pairing; adjacent pairing concentrates 31 active iters in the last
// block and lengthens the makespan (R3 regression, +7.6 us).
// SWAPPED QK^T (T12): s = mfma(K, Q) so each lane holds S[t=nb*16+q*4+i]
// [srow=ln] -> P-write is 4x ds_write_b64 via v_cvt_pk_bf16_f32, l-partial
// one scalar per lane. No setprio: all 8 waves are barrier-locked each
// iteration (m190 regime, not m191).
// Faithful reshape: z[b,h,s,d] -> Z'[b][h*64 + s/16][(s%16)*64 + d]
// ---------------------------------------------------------------------------
__global__ __launch_bounds__(512) void attn_k(const ushort* __restrict__ qkv,
                                              const ushort* __restrict__ vt,
                                              ushort* __restrict__ zp) {
    __shared__ ushort Ks[2][64 * 64];
    __shared__ ushort Vs[2][64 * 64];
    __shared__ ushort P[8][16 * 76];
    int pr = blockIdx.x;
    int bh = blockIdx.y;
    int b = bh >> 4, h = bh & 15;
    int t = threadIdx.x;
    int w = t >> 6;
    int grp = w >> 2;
    int lane = t & 63, q = lane >> 4, ln = lane & 15;

    const float CE = 0.72134752f;    // 0.5 * log2(e)

    const ushort* Qp = qkv + (size_t)(b * SEQ) * NQKV + h * 64;
    const ushort* Kp = qkv + (size_t)(b * SEQ) * NQKV + 1024 + h * 64;
    const ushort* Vt = vt + (size_t)bh * 64 * 1024;

    int row0 = t >> 3, kc0 = (t & 7) ^ (row0 & 7);

    int tiB = 15 - pr;
    int ti = grp ? tiB : pr;
    int sw = ti * 64 + (w & 3) * 16;

    short8 aq0 = *(const short8*)(Qp + (size_t)(sw + ln) * NQKV + q * 8);
    short8 aq1 = *(const short8*)(Qp + (size_t)(sw + ln) * NQKV + 32 + q * 8);

    float lp = 0.f;
    float4v o[4];
#pragma unroll
    for (int nb = 0; nb < 4; nb++) o[nb] = (float4v){0.f, 0.f, 0.f, 0.f};

    gl2lds16(Kp + (size_t)row0 * NQKV + kc0 * 8, &Ks[0][t * 8]);
    gl2lds16(Vt + (size_t)row0 * 1024 + kc0 * 8, &Vs[0][t * 8]);

    int srow_l = sw + ln;   // this lane's q-row (post-swap: srow = ln axis)

    for (int kt = 0; kt <= tiB; kt++) {
        int cur = kt & 1;
        int t0 = kt * 64;
        __syncthreads();
        if (kt < tiB) {
            int nt0 = t0 + 64, nxt = cur ^ 1;
            gl2lds16(Kp + (size_t)(nt0 + row0) * NQKV + kc0 * 8, &Ks[nxt][t * 8]);
            gl2lds16(Vt + (size_t)row0 * 1024 + nt0 + kc0 * 8, &Vs[nxt][t * 8]);
        }
        if (kt <= ti) {
            float4v s[4];
#pragma unroll
            for (int nb = 0; nb < 4; nb++) {
                int row = nb * 16 + ln;
                short8 kf0 = *(const short8*)&Ks[cur][((row << 3) | (q ^ (row & 7))) * 8];
                short8 kf1 = *(const short8*)&Ks[cur][((row << 3) | ((4 + q) ^ (row & 7))) * 8];
                s[nb] = (float4v){0.f, 0.f, 0.f, 0.f};
                s[nb] = __builtin_amdgcn_mfma_f32_16x16x32_bf16(kf0, aq0, s[nb], 0, 0, 0);
                s[nb] = __builtin_amdgcn_mfma_f32_16x16x32_bf16(kf1, aq1, s[nb], 0, 0, 0);
            }
            float p[4][4];
            if (kt < ti) {
#pragma unroll
                for (int nb = 0; nb < 4; nb++)
#pragma unroll
                    for (int i = 0; i < 4; i++) p[nb][i] = exp2f(s[nb][i] * CE);
            } else {
#pragma unroll
                for (int nb = 0; nb < 4; nb++)
#pragma unroll
                    for (int i = 0; i < 4; i++) {
                        int tcol = t0 + nb * 16 + q * 4 + i;
                        p[nb][i] = exp2f((tcol <= srow_l) ? s[nb][i] * CE : -1e30f);
                    }
            }
#pragma unroll
            for (int nb = 0; nb < 4; nb++)
                lp += (p[nb][0] + p[nb][1]) + (p[nb][2] + p[nb][3]);
#pragma unroll
            for (int nb = 0; nb < 4; nb++) {
                uint2 pk;
                pk.x = cvt_pk_bf16(p[nb][0], p[nb][1]);
                pk.y = cvt_pk_bf16(p[nb][2], p[nb][3]);
                *(uint2*)&P[w][ln * 76 + nb * 16 + q * 4] = pk;
            }
            asm volatile("s_waitcnt lgkmcnt(0)\n" ::: "memory");
            short8 ap0 = *(const short8*)&P[w][ln * 76 + q * 8];
            short8 ap1 = *(const short8*)&P[w][ln * 76 + 32 + q * 8];
#pragma unroll
            for (int nb = 0; nb < 4; nb++) {
                int row = nb * 16 + ln;
                short8 bv0 = *(const short8*)&Vs[cur][((row << 3) | (q ^ (row & 7))) * 8];
                short8 bv1 = *(const short8*)&Vs[cur][((row << 3) | ((4 + q) ^ (row & 7))) * 8];
                o[nb] = __builtin_amdgcn_mfma_f32_16x16x32_bf16(ap0, bv0, o[nb], 0, 0, 0);
                o[nb] = __builtin_amdgcn_mfma_f32_16x16x32_bf16(ap1, bv1, o[nb], 0, 0, 0);
            }
        }
    }

    // l[srow=ln] lives per-lane; reduce partial sums across the q axis.
    float lred = lp;
    lred += __shfl_xor(lred, 16, 64);
    lred += __shfl_xor(lred, 32, 64);
    // broadcast l for the o-fragment rows (srow = sw + q*4 + i)
    float l_i[4];
#pragma unroll
    for (int i = 0; i < 4; i++)
        l_i[i] = __shfl(lred, (q << 4) | (q * 4 + i), 64);

#pragma unroll
    for (int nb = 0; nb < 4; nb++) {
#pragma unroll
        for (int i = 0; i < 4; i++) {
            int srow = sw + q * 4 + i;
            int d = nb * 16 + ln;
            float z = o[nb][i] / l_i[i];
            int sp = h * 64 + (srow >> 4);
            int ep = ((srow & 15) << 6) + d;
            zp[((size_t)(b * SEQ + sp)) * 1024 + ep] = f2bf(z);
        }
    }
}

// ---------------------------------------------------------------------------
extern "C" void kernel_launch(void* const* d_in, const int* in_sizes, int n_in,
                              void* d_out, int out_size, void* d_ws, size_t ws_size,
                              hipStream_t stream) {
    const void* X  = d_in[0];
    // d_in[1] = mask (causal; applied structurally)
    const void* wq = d_in[2];
    const void* bq = d_in[3];
    const void* wk = d_in[4];
    const void* bk = d_in[5];
    const void* wv = d_in[6];
    const void* bv = d_in[7];
    const void* wo = d_in[8];
    const void* bo = d_in[9];

    char* ws = (char*)d_ws;
    int*    flag  = (int*)ws;                          // [0, 4096)
    ushort* biasq = (ushort*)(ws + 4096);              // 4096 bf16: [bq|bk|bv|bo]
    ushort* WTall = (ushort*)(ws + 12288);             // 4x 1024x1024 bf16 [wq|wk|wv|wo]
    ushort* Xc    = (ushort*)(ws + 8400896);           // 4096x1024 bf16 (fp32 path)
    ushort* QKV   = (ushort*)(ws + 16789504);          // 4096x3072 bf16
    ushort* VT    = (ushort*)(ws + 41955328);          // 64 x 64 x 1024 bf16
    ushort* WTo   = WTall + 3 * 1024 * 1024;
    ushort* ZP    = Xc;                                // alias: Xc dead after QKV gemm

    prep_k<<<5136, 256, 0, stream>>>(X, wq, wk, wv, wo, bq, bk, bv, bo,
                                     Xc, biasq, WTall, flag);
    gemm_k<128, false, true><<<dim3(24, 32), 256, 0, stream>>>(
        (const ushort*)X, Xc, WTall, biasq, QKV, VT, flag, 4096, NQKV, 1024);
    attn_k<<<dim3(8, 64), 512, 0, stream>>>(QKV, VT, ZP);
    gemm_k<64, true, false><<<dim3(8, 64), 256, 0, stream>>>(
        ZP, ZP, WTo, biasq + 3072, d_out, nullptr, flag, 4096, 1024, 1024);
}

// Round 5
// 180.402 us; speedup vs baseline: 1.0826x; 1.0204x over previous
//
#include <hip/hip_runtime.h>
#include <hip/hip_bf16.h>
#include <stdint.h>

typedef __attribute__((ext_vector_type(8))) short short8;
typedef __attribute__((ext_vector_type(4))) float float4v;

#define SEQ   1024
#define NQKV  3072

__device__ __forceinline__ float bf2f(ushort h) {
    union { uint u; float f; } c; c.u = ((uint)h) << 16; return c.f;
}
__device__ __forceinline__ ushort f2bf(float f) {
    union { uint u; float f; } c; c.f = f;
    uint u = c.u;
    return (ushort)((u + 0x7fffu + ((u >> 16) & 1u)) >> 16);
}
__device__ __forceinline__ uint cvt_pk_bf16(float lo, float hi) {
    uint r;
    asm volatile("v_cvt_pk_bf16_f32 %0, %1, %2" : "=v"(r) : "v"(lo), "v"(hi));
    return r;
}
__device__ __forceinline__ void gl2lds16(const ushort* g, ushort* l) {
    __builtin_amdgcn_global_load_lds(
        (const __attribute__((address_space(1))) unsigned int*)(g),
        (__attribute__((address_space(3))) unsigned int*)(l),
        16, 0, 0);
}

// ---------------------------------------------------------------------------
// prep_k: fused detect + X-convert + bias-concat + 4x weight transpose.
// ---------------------------------------------------------------------------
__global__ __launch_bounds__(256) void prep_k(const void* __restrict__ X,
                                              const void* __restrict__ w0,
                                              const void* __restrict__ w1,
                                              const void* __restrict__ w2,
                                              const void* __restrict__ w3,
                                              const void* __restrict__ bq,
                                              const void* __restrict__ bk,
                                              const void* __restrict__ bv,
                                              const void* __restrict__ bo,
                                              ushort* __restrict__ xc,
                                              ushort* __restrict__ biasout,
                                              ushort* __restrict__ wtall,
                                              int* __restrict__ flag) {
    __shared__ int tot;
    __shared__ ushort tile[64][72];
    int t = threadIdx.x;
    if (t == 0) tot = 0;
    __syncthreads();
    uint wv = ((const uint*)X)[t];
    uint e = (wv >> 7) & 0xFFu;
    bool isbf = (e >= 100u && e <= 130u);
    unsigned long long m = __ballot(isbf);
    if ((t & 63) == 0) atomicAdd(&tot, __popcll(m));
    __syncthreads();
    bool isf = (tot <= 128);   // true -> fp32 input

    int bi = blockIdx.x;
    if (bi == 0 && t == 0) flag[0] = isf ? 1 : 0;

    if (bi < 4096) {
        if (!isf) return;
        int i = (bi * 256 + t) * 4;
        float4 v = *(const float4*)((const float*)X + i);
        ushort4 o;
        o.x = f2bf(v.x); o.y = f2bf(v.y); o.z = f2bf(v.z); o.w = f2bf(v.w);
        *(ushort4*)(xc + i) = o;
    } else if (bi < 4112) {
        int i = (bi - 4096) * 256 + t;
        int sel = i >> 10, j = i & 1023;
        const void* p = (sel == 0) ? bq : (sel == 1) ? bk : (sel == 2) ? bv : bo;
        biasout[i] = isf ? f2bf(((const float*)p)[j]) : ((const ushort*)p)[j];
    } else {
        int idx = bi - 4112;
        int z = idx >> 8, rem = idx & 255;
        const void* in = (z == 0) ? w0 : (z == 1) ? w1 : (z == 2) ? w2 : w3;
        ushort* out = wtall + (size_t)z * 1024 * 1024;
        int k0 = (rem & 15) * 64, n0 = (rem >> 4) * 64;
        int r = t >> 3, c = (t & 7) * 8;
#pragma unroll
        for (int p = 0; p < 2; p++) {
            int rr = r + p * 32;
            if (isf) {
                const float* src = (const float*)in + (size_t)(k0 + rr) * 1024 + n0 + c;
                float4 v0 = *(const float4*)src;
                float4 v1 = *(const float4*)(src + 4);
                tile[rr][c + 0] = f2bf(v0.x); tile[rr][c + 1] = f2bf(v0.y);
                tile[rr][c + 2] = f2bf(v0.z); tile[rr][c + 3] = f2bf(v0.w);
                tile[rr][c + 4] = f2bf(v1.x); tile[rr][c + 5] = f2bf(v1.y);
                tile[rr][c + 6] = f2bf(v1.z); tile[rr][c + 7] = f2bf(v1.w);
            } else {
                uint4 v = *(const uint4*)((const ushort*)in + (size_t)(k0 + rr) * 1024 + n0 + c);
                *(uint4*)&tile[rr][c] = v;
            }
        }
        __syncthreads();
#pragma unroll
        for (int p = 0; p < 2; p++) {
            int n = r + p * 32;
            ushort vals[8];
#pragma unroll
            for (int j = 0; j < 8; j++) vals[j] = tile[c + j][n];
            *(uint4*)(out + (size_t)(n0 + n) * 1024 + k0 + c) = *(uint4*)vals;
        }
    }
}

// ---------------------------------------------------------------------------
// GEMM, BK=32 DOUBLE-BUFFERED, single barrier per K-iter, BM x 128 tile,
// 4 waves (2x2). BK=32 (32 KB LDS) is deliberate: BK=64 (64 KB) drops
// occupancy 2 blocks/CU -> 1 and REGRESSED 43.9 -> 48.4 us (R4); the
// co-resident block is what hides the barrier drain (m114/m132 mechanism).
// Chunk swizzle slot = kc ^ ((row>>1)&3) (conflict-free, R7-verified).
// T1 XCD swizzle: nwg % 8 == 0 for both uses (768, 512); each XCD gets a
// contiguous tile chunk -> A-panel reuse lands in one XCD L2.
// WRV: QKV V-third blocks also emit VT[bh][d][t] from the accumulator
// (4 consecutive tokens per lane -> ushort4 store), replacing vtrans_k.
// ---------------------------------------------------------------------------
template <int BM, bool DUAL, bool WRV>
__global__ __launch_bounds__(256) void gemm_k(const ushort* __restrict__ Araw,
                                              const ushort* __restrict__ Aconv,
                                              const ushort* __restrict__ BT,
                                              const ushort* __restrict__ bias,
                                              void* __restrict__ C,
                                              ushort* __restrict__ vt,
                                              const int* __restrict__ flag,
                                              int M, int N, int K) {
    constexpr int RM = BM / 32;   // M-frags per wave
    constexpr int AJ = BM / 64;   // A-chunks per thread (BM*4/256)
    __shared__ ushort As[2][BM * 32];
    __shared__ ushort Bs[2][128 * 32];
    int nwgx = gridDim.x;
    int orig = blockIdx.y * nwgx + blockIdx.x;
    int cpx = (nwgx * gridDim.y) >> 3;
    int swz = (orig & 7) * cpx + (orig >> 3);
    int n0 = (swz % nwgx) * 128, m0 = (swz / nwgx) * BM;
    int t = threadIdx.x;
    int w = t >> 6, lane = t & 63, q = lane >> 4, ln = lane & 15;
    int wr = w >> 1, wc = w & 1;
    const ushort* A = (*flag) ? Aconv : Araw;

    float4v acc[RM][4];
#pragma unroll
    for (int r = 0; r < RM; r++)
#pragma unroll
        for (int cc = 0; cc < 4; cc++) acc[r][cc] = (float4v){0.f, 0.f, 0.f, 0.f};

    // prologue: stage k0=0 into buf 0
#pragma unroll
    for (int j = 0; j < AJ; j++) {
        int c = j * 256 + t;
        int row = c >> 2, s = c & 3;
        int kc = s ^ ((row >> 1) & 3);
        gl2lds16(A + (size_t)(m0 + row) * K + kc * 8, &As[0][c * 8]);
    }
#pragma unroll
    for (int j = 0; j < 2; j++) {
        int c = j * 256 + t;
        int row = c >> 2, s = c & 3;
        int kc = s ^ ((row >> 1) & 3);
        gl2lds16(BT + (size_t)(n0 + row) * K + kc * 8, &Bs[0][c * 8]);
    }

    int nIter = K >> 5;
    for (int kt = 0; kt < nIter; kt++) {
        int cur = kt & 1;
        __syncthreads();   // buf[cur] staged; buf[cur^1] reads complete
        if (kt + 1 < nIter) {
            int nk0 = (kt + 1) << 5, nxt = cur ^ 1;
#pragma unroll
            for (int j = 0; j < AJ; j++) {
                int c = j * 256 + t;
                int row = c >> 2, s = c & 3;
                int kc = s ^ ((row >> 1) & 3);
                gl2lds16(A + (size_t)(m0 + row) * K + nk0 + kc * 8, &As[nxt][c * 8]);
            }
#pragma unroll
            for (int j = 0; j < 2; j++) {
                int c = j * 256 + t;
                int row = c >> 2, s = c & 3;
                int kc = s ^ ((row >> 1) & 3);
                gl2lds16(BT + (size_t)(n0 + row) * K + nk0 + kc * 8, &Bs[nxt][c * 8]);
            }
        }
        short8 af[RM], bf[4];
#pragma unroll
        for (int r = 0; r < RM; r++) {
            int row = wr * (BM / 2) + r * 16 + ln;
            af[r] = *(const short8*)&As[cur][((row << 2) | (q ^ ((row >> 1) & 3))) * 8];
        }
#pragma unroll
        for (int cc = 0; cc < 4; cc++) {
            int col = wc * 64 + cc * 16 + ln;
            bf[cc] = *(const short8*)&Bs[cur][((col << 2) | (q ^ ((col >> 1) & 3))) * 8];
        }
#pragma unroll
        for (int r = 0; r < RM; r++)
#pragma unroll
            for (int cc = 0; cc < 4; cc++)
                acc[r][cc] = __builtin_amdgcn_mfma_f32_16x16x32_bf16(af[r], bf[cc], acc[r][cc], 0, 0, 0);
    }

    bool outf = DUAL && (*flag != 0);
    bool wrv = WRV && (n0 >= 2048);
#pragma unroll
    for (int cc = 0; cc < 4; cc++) {
        int n = n0 + wc * 64 + cc * 16 + ln;
        float bs = bf2f(bias[n]);
#pragma unroll
        for (int r = 0; r < RM; r++) {
            ushort pk[4];
#pragma unroll
            for (int i = 0; i < 4; i++) {
                int m = m0 + wr * (BM / 2) + r * 16 + q * 4 + i;
                float v = acc[r][cc][i] + bs;
                if (outf) ((float*)C)[(size_t)m * N + n] = v;
                else      ((ushort*)C)[(size_t)m * N + n] = f2bf(v);
                pk[i] = f2bf(v);
            }
            if (wrv) {
                int mb = m0 + wr * (BM / 2) + r * 16 + q * 4;   // 4 consecutive tokens
                int b = mb >> 10, trow = mb & 1023;
                int h = (n - 2048) >> 6, d = n & 63;
                *(ushort4*)(vt + (((size_t)(b * 16 + h) * 64 + d) * 1024 + trow)) = *(ushort4*)pk;
            }
        }
    }
}

// ---------------------------------------------------------------------------
// Flash attention, causal, WAVE-SPLIT shared-prefix dual-tile (pr, 15-pr),
// pipelined, no-max softmax. Balanced: every block does exactly 17 active
// wave-group iterations (group A: pr+1, group B: 16-pr) -- do NOT pair
// adjacent tiles (R3 regression, +7.6 us: concentrates 31 iters in one
// block). CU-pairing balance: with 512 blocks = 2/CU, round-robin pairs
// linear id with id+256 (same blockIdx.x) -> same pr -> worst CU gets two
// 16-iter blocks (32 units vs avg 25). Relabel pr = 7-x for bh>=32 so
// paired blocks sum to (16-x)+(9+x) = 25 constant. Pure bijective
// relabeling; per-block work and math unchanged.
// SWAPPED QK^T (T12): s = mfma(K, Q) so each lane holds S[t=nb*16+q*4+i]
// [srow=ln] -> P-write is 4x ds_write_b64 via v_cvt_pk_bf16_f32, l-partial
// one scalar per lane. No setprio (m190 regime: all waves barrier-locked).
// Faithful reshape: z[b,h,s,d] -> Z'[b][h*64 + s/16][(s%16)*64 + d]
// ---------------------------------------------------------------------------
__global__ __launch_bounds__(512) void attn_k(const ushort* __restrict__ qkv,
                                              const ushort* __restrict__ vt,
                                              ushort* __restrict__ zp) {
    __shared__ ushort Ks[2][64 * 64];
    __shared__ ushort Vs[2][64 * 64];
    __shared__ ushort P[8][16 * 76];
    int bh = blockIdx.y;
    int pr = (bh & 32) ? (7 - blockIdx.x) : blockIdx.x;
    int b = bh >> 4, h = bh & 15;
    int t = threadIdx.x;
    int w = t >> 6;
    int grp = w >> 2;
    int lane = t & 63, q = lane >> 4, ln = lane & 15;

    const float CE = 0.72134752f;    // 0.5 * log2(e)

    const ushort* Qp = qkv + (size_t)(b * SEQ) * NQKV + h * 64;
    const ushort* Kp = qkv + (size_t)(b * SEQ) * NQKV + 1024 + h * 64;
    const ushort* Vt = vt + (size_t)bh * 64 * 1024;

    int row0 = t >> 3, kc0 = (t & 7) ^ (row0 & 7);

    int tiB = 15 - pr;
    int ti = grp ? tiB : pr;
    int sw = ti * 64 + (w & 3) * 16;

    short8 aq0 = *(const short8*)(Qp + (size_t)(sw + ln) * NQKV + q * 8);
    short8 aq1 = *(const short8*)(Qp + (size_t)(sw + ln) * NQKV + 32 + q * 8);

    float lp = 0.f;
    float4v o[4];
#pragma unroll
    for (int nb = 0; nb < 4; nb++) o[nb] = (float4v){0.f, 0.f, 0.f, 0.f};

    gl2lds16(Kp + (size_t)row0 * NQKV + kc0 * 8, &Ks[0][t * 8]);
    gl2lds16(Vt + (size_t)row0 * 1024 + kc0 * 8, &Vs[0][t * 8]);

    int srow_l = sw + ln;   // this lane's q-row (post-swap: srow = ln axis)

    for (int kt = 0; kt <= tiB; kt++) {
        int cur = kt & 1;
        int t0 = kt * 64;
        __syncthreads();
        if (kt < tiB) {
            int nt0 = t0 + 64, nxt = cur ^ 1;
            gl2lds16(Kp + (size_t)(nt0 + row0) * NQKV + kc0 * 8, &Ks[nxt][t * 8]);
            gl2lds16(Vt + (size_t)row0 * 1024 + nt0 + kc0 * 8, &Vs[nxt][t * 8]);
        }
        if (kt <= ti) {
            float4v s[4];
#pragma unroll
            for (int nb = 0; nb < 4; nb++) {
                int row = nb * 16 + ln;
                short8 kf0 = *(const short8*)&Ks[cur][((row << 3) | (q ^ (row & 7))) * 8];
                short8 kf1 = *(const short8*)&Ks[cur][((row << 3) | ((4 + q) ^ (row & 7))) * 8];
                s[nb] = (float4v){0.f, 0.f, 0.f, 0.f};
                s[nb] = __builtin_amdgcn_mfma_f32_16x16x32_bf16(kf0, aq0, s[nb], 0, 0, 0);
                s[nb] = __builtin_amdgcn_mfma_f32_16x16x32_bf16(kf1, aq1, s[nb], 0, 0, 0);
            }
            float p[4][4];
            if (kt < ti) {
#pragma unroll
                for (int nb = 0; nb < 4; nb++)
#pragma unroll
                    for (int i = 0; i < 4; i++) p[nb][i] = exp2f(s[nb][i] * CE);
            } else {
#pragma unroll
                for (int nb = 0; nb < 4; nb++)
#pragma unroll
                    for (int i = 0; i < 4; i++) {
                        int tcol = t0 + nb * 16 + q * 4 + i;
                        p[nb][i] = exp2f((tcol <= srow_l) ? s[nb][i] * CE : -1e30f);
                    }
            }
#pragma unroll
            for (int nb = 0; nb < 4; nb++)
                lp += (p[nb][0] + p[nb][1]) + (p[nb][2] + p[nb][3]);
#pragma unroll
            for (int nb = 0; nb < 4; nb++) {
                uint2 pk;
                pk.x = cvt_pk_bf16(p[nb][0], p[nb][1]);
                pk.y = cvt_pk_bf16(p[nb][2], p[nb][3]);
                *(uint2*)&P[w][ln * 76 + nb * 16 + q * 4] = pk;
            }
            asm volatile("s_waitcnt lgkmcnt(0)\n" ::: "memory");
            short8 ap0 = *(const short8*)&P[w][ln * 76 + q * 8];
            short8 ap1 = *(const short8*)&P[w][ln * 76 + 32 + q * 8];
#pragma unroll
            for (int nb = 0; nb < 4; nb++) {
                int row = nb * 16 + ln;
                short8 bv0 = *(const short8*)&Vs[cur][((row << 3) | (q ^ (row & 7))) * 8];
                short8 bv1 = *(const short8*)&Vs[cur][((row << 3) | ((4 + q) ^ (row & 7))) * 8];
                o[nb] = __builtin_amdgcn_mfma_f32_16x16x32_bf16(ap0, bv0, o[nb], 0, 0, 0);
                o[nb] = __builtin_amdgcn_mfma_f32_16x16x32_bf16(ap1, bv1, o[nb], 0, 0, 0);
            }
        }
    }

    // l[srow=ln] lives per-lane; reduce partial sums across the q axis.
    float lred = lp;
    lred += __shfl_xor(lred, 16, 64);
    lred += __shfl_xor(lred, 32, 64);
    // broadcast l for the o-fragment rows (srow = sw + q*4 + i)
    float l_i[4];
#pragma unroll
    for (int i = 0; i < 4; i++)
        l_i[i] = __shfl(lred, (q << 4) | (q * 4 + i), 64);

#pragma unroll
    for (int nb = 0; nb < 4; nb++) {
#pragma unroll
        for (int i = 0; i < 4; i++) {
            int srow = sw + q * 4 + i;
            int d = nb * 16 + ln;
            float z = o[nb][i] / l_i[i];
            int sp = h * 64 + (srow >> 4);
            int ep = ((srow & 15) << 6) + d;
            zp[((size_t)(b * SEQ + sp)) * 1024 + ep] = f2bf(z);
        }
    }
}

// ---------------------------------------------------------------------------
extern "C" void kernel_launch(void* const* d_in, const int* in_sizes, int n_in,
                              void* d_out, int out_size, void* d_ws, size_t ws_size,
                              hipStream_t stream) {
    const void* X  = d_in[0];
    // d_in[1] = mask (causal; applied structurally)
    const void* wq = d_in[2];
    const void* bq = d_in[3];
    const void* wk = d_in[4];
    const void* bk = d_in[5];
    const void* wv = d_in[6];
    const void* bv = d_in[7];
    const void* wo = d_in[8];
    const void* bo = d_in[9];

    char* ws = (char*)d_ws;
    int*    flag  = (int*)ws;                          // [0, 4096)
    ushort* biasq = (ushort*)(ws + 4096);              // 4096 bf16: [bq|bk|bv|bo]
    ushort* WTall = (ushort*)(ws + 12288);             // 4x 1024x1024 bf16 [wq|wk|wv|wo]
    ushort* Xc    = (ushort*)(ws + 8400896);           // 4096x1024 bf16 (fp32 path)
    ushort* QKV   = (ushort*)(ws + 16789504);          // 4096x3072 bf16
    ushort* VT    = (ushort*)(ws + 41955328);          // 64 x 64 x 1024 bf16
    ushort* WTo   = WTall + 3 * 1024 * 1024;
    ushort* ZP    = Xc;                                // alias: Xc dead after QKV gemm

    prep_k<<<5136, 256, 0, stream>>>(X, wq, wk, wv, wo, bq, bk, bv, bo,
                                     Xc, biasq, WTall, flag);
    gemm_k<128, false, true><<<dim3(24, 32), 256, 0, stream>>>(
        (const ushort*)X, Xc, WTall, biasq, QKV, VT, flag, 4096, NQKV, 1024);
    attn_k<<<dim3(8, 64), 512, 0, stream>>>(QKV, VT, ZP);
    gemm_k<64, true, false><<<dim3(8, 64), 256, 0, stream>>>(
        ZP, ZP, WTo, biasq + 3072, d_out, nullptr, flag, 4096, 1024, 1024);
}